// Round 1
// baseline (189.229 us; speedup 1.0000x reference)
//
#include <hip/hip_runtime.h>
#include <math.h>

typedef __attribute__((ext_vector_type(8))) short bf16x8;
typedef __attribute__((ext_vector_type(4))) float f32x4;

static __device__ __forceinline__ unsigned short f2b(float x) {
  unsigned int u = __float_as_uint(x);
  u += 0x7FFFu + ((u >> 16) & 1u);  // round-to-nearest-even
  return (unsigned short)(u >> 16);
}

// ---------------- prep kernels ----------------
// W1 [256][512] -> W1T bf16 [512][256]; W2 [512][256] -> W2T bf16 [256][512];
// memory [50][256] -> memB bf16 [64][256] (zero-padded rows)
__global__ void prep_weights(const float* __restrict__ W1,
                             const float* __restrict__ W2,
                             const float* __restrict__ mem,
                             unsigned short* __restrict__ W1T,
                             unsigned short* __restrict__ W2T,
                             unsigned short* __restrict__ memB) {
  int i = blockIdx.x * 256 + threadIdx.x;
  if (i < 131072) {
    int k = i >> 9, n = i & 511;            // W1[k][n]
    W1T[n * 256 + k] = f2b(W1[i]);
  } else if (i < 262144) {
    int j = i - 131072;
    int k = j >> 8, n = j & 255;            // W2[k][n]
    W2T[n * 512 + k] = f2b(W2[j]);
  } else if (i < 278528) {
    int j = i - 262144;
    int r = j >> 8;
    memB[j] = (r < 50) ? f2b(mem[j]) : (unsigned short)0;
  }
}

__global__ void prep_msq(const float* __restrict__ mem, float* __restrict__ msq) {
  int r = blockIdx.x;  // 64 blocks x 64 threads
  float s = 0.f;
  if (r < 50) {
    for (int c = threadIdx.x; c < 256; c += 64) {
      float v = mem[r * 256 + c];
      s += v * v;
    }
  }
  for (int m = 1; m < 64; m <<= 1) s += __shfl_xor(s, m, 64);
  if (threadIdx.x == 0) msq[r] = (r < 50) ? s : 1e30f;
}

// ---------------- fused main kernel ----------------
// 64 tokens per block. GEMM1 produces H^T chunks (128 hcols at a time) in LDS,
// GEMM2 accumulates F^T in registers, LN in-register, feats bf16 back to LDS,
// dots GEMM vs memory, top-5 + sigmoid epilogue.
#define XP 264   // Xs / feats pitch (bf16 elems): 256 + 8 pad
#define HP 136   // Hs pitch (bf16 elems): 128 + 8 pad
#define DPitch 68

__global__ __launch_bounds__(256, 2) void fused_main(
    const float* __restrict__ X, const float* __restrict__ b1v,
    const float* __restrict__ b2v, const float* __restrict__ gammav,
    const float* __restrict__ betav, const unsigned short* __restrict__ W1T,
    const unsigned short* __restrict__ W2T,
    const unsigned short* __restrict__ memB, const float* __restrict__ msq,
    float* __restrict__ out) {
  __shared__ __align__(16) char smem[55040];
  unsigned short* Xs = (unsigned short*)smem;            // [64][264] bf16; later feats
  unsigned short* Hs = (unsigned short*)(smem + 33792);  // [64][136] bf16; later distS
  float* distS = (float*)(smem + 33792);                 // [64][68] fp32
  float* red = (float*)(smem + 51200);
  float* psum   = red;        // [4][64]
  float* psumsq = red + 256;  // [4][64]
  float* fsqp   = red + 512;  // [4][64]
  float* muS    = red + 768;  // [64]
  float* rstdS  = red + 832;  // [64]
  float* fsqS   = red + 896;  // [64]

  const int tid = threadIdx.x;
  const int wid = tid >> 6;
  const int lane = tid & 63;
  const int l16 = lane & 15;
  const int quad = lane >> 4;

  // ---- Phase 0: stage X tile [64][256] fp32 -> LDS bf16 ----
  const float4* X4 = (const float4*)(X + (size_t)blockIdx.x * 64 * 256);
#pragma unroll
  for (int j = 0; j < 16; ++j) {
    int idx = j * 256 + tid;  // over [64 rows][64 float4]
    float4 v = X4[idx];
    int row = idx >> 6, c4 = (idx & 63) << 2;
    unsigned int p0 = f2b(v.x) | ((unsigned int)f2b(v.y) << 16);
    unsigned int p1 = f2b(v.z) | ((unsigned int)f2b(v.w) << 16);
    *(uint2*)(&Xs[row * XP + c4]) = make_uint2(p0, p1);
  }

  // F^T accumulators: value at (fcol = wid*64+mt*16+quad*4+reg, token = nt*16+l16)
  f32x4 acc2[4][4];
#pragma unroll
  for (int mt = 0; mt < 4; ++mt) {
    const float4 bb = *(const float4*)(&b2v[wid * 64 + mt * 16 + quad * 4]);
#pragma unroll
    for (int nt = 0; nt < 4; ++nt) {
      acc2[mt][nt][0] = bb.x; acc2[mt][nt][1] = bb.y;
      acc2[mt][nt][2] = bb.z; acc2[mt][nt][3] = bb.w;
    }
  }

  __syncthreads();

  // ---- Phase 1: chunked GEMM1 -> relu -> Hs; GEMM2 accumulate ----
  for (int cc = 0; cc < 4; ++cc) {
    // GEMM1: M = 32 hcols (this wave), N = 64 tokens, K = 256
    int hbase = cc * 128 + wid * 32;
    f32x4 acc1[2][4];
#pragma unroll
    for (int mt = 0; mt < 2; ++mt) {
      const float4 bb = *(const float4*)(&b1v[hbase + mt * 16 + quad * 4]);
#pragma unroll
      for (int nt = 0; nt < 4; ++nt) {
        acc1[mt][nt][0] = bb.x; acc1[mt][nt][1] = bb.y;
        acc1[mt][nt][2] = bb.z; acc1[mt][nt][3] = bb.w;
      }
    }
#pragma unroll
    for (int kk = 0; kk < 8; ++kk) {
      int k0 = kk * 32 + quad * 8;
      bf16x8 a[2], b[4];
#pragma unroll
      for (int mt = 0; mt < 2; ++mt)
        a[mt] = *(const bf16x8*)(W1T + (hbase + mt * 16 + l16) * 256 + k0);
#pragma unroll
      for (int nt = 0; nt < 4; ++nt)
        b[nt] = *(const bf16x8*)(Xs + (nt * 16 + l16) * XP + k0);
#pragma unroll
      for (int mt = 0; mt < 2; ++mt)
#pragma unroll
        for (int nt = 0; nt < 4; ++nt)
          acc1[mt][nt] = __builtin_amdgcn_mfma_f32_16x16x32_bf16(
              a[mt], b[nt], acc1[mt][nt], 0, 0, 0);
    }
    __syncthreads();  // previous GEMM2 done reading Hs
    // epilogue: relu -> bf16 -> Hs[token][hcol_local] (4 consecutive hcols/lane)
#pragma unroll
    for (int mt = 0; mt < 2; ++mt) {
#pragma unroll
      for (int nt = 0; nt < 4; ++nt) {
        int token = nt * 16 + l16;
        int hloc = wid * 32 + mt * 16 + quad * 4;
        f32x4 v = acc1[mt][nt];
        unsigned int p0 = f2b(fmaxf(v[0], 0.f)) | ((unsigned int)f2b(fmaxf(v[1], 0.f)) << 16);
        unsigned int p1 = f2b(fmaxf(v[2], 0.f)) | ((unsigned int)f2b(fmaxf(v[3], 0.f)) << 16);
        *(uint2*)(&Hs[token * HP + hloc]) = make_uint2(p0, p1);
      }
    }
    __syncthreads();
    // GEMM2 partial: F^T += W2T[:, cc*128:+128] x Hs
#pragma unroll
    for (int k2 = 0; k2 < 4; ++k2) {
      int k0 = k2 * 32 + quad * 8;
      bf16x8 a[4], b[4];
#pragma unroll
      for (int mt = 0; mt < 4; ++mt)
        a[mt] = *(const bf16x8*)(W2T + (wid * 64 + mt * 16 + l16) * 512 + cc * 128 + k0);
#pragma unroll
      for (int nt = 0; nt < 4; ++nt)
        b[nt] = *(const bf16x8*)(Hs + (nt * 16 + l16) * HP + k0);
#pragma unroll
      for (int mt = 0; mt < 4; ++mt)
#pragma unroll
        for (int nt = 0; nt < 4; ++nt)
          acc2[mt][nt] = __builtin_amdgcn_mfma_f32_16x16x32_bf16(
              a[mt], b[nt], acc2[mt][nt], 0, 0, 0);
    }
  }

  // ---- Phase 2a: per-token sum/sumsq for LayerNorm ----
#pragma unroll
  for (int nt = 0; nt < 4; ++nt) {
    float s = 0.f, sq = 0.f;
#pragma unroll
    for (int mt = 0; mt < 4; ++mt)
#pragma unroll
      for (int r = 0; r < 4; ++r) {
        float v = acc2[mt][nt][r];
        s += v; sq += v * v;
      }
    s += __shfl_xor(s, 16, 64); sq += __shfl_xor(sq, 16, 64);
    s += __shfl_xor(s, 32, 64); sq += __shfl_xor(sq, 32, 64);
    if (quad == 0) {
      psum[wid * 64 + nt * 16 + l16] = s;
      psumsq[wid * 64 + nt * 16 + l16] = sq;
    }
  }
  __syncthreads();
  if (tid < 64) {
    float s = psum[tid] + psum[64 + tid] + psum[128 + tid] + psum[192 + tid];
    float sq = psumsq[tid] + psumsq[64 + tid] + psumsq[128 + tid] + psumsq[192 + tid];
    float mu = s * (1.f / 256.f);
    float var = sq * (1.f / 256.f) - mu * mu;
    muS[tid] = mu;
    rstdS[tid] = rsqrtf(var + 1e-5f);
  }
  __syncthreads();

  // ---- Phase 2b: normalize in-register, write feats bf16 (token-major), fsq ----
  {
    float4 g[4], be[4];
#pragma unroll
    for (int mt = 0; mt < 4; ++mt) {
      g[mt]  = *(const float4*)(&gammav[wid * 64 + mt * 16 + quad * 4]);
      be[mt] = *(const float4*)(&betav[wid * 64 + mt * 16 + quad * 4]);
    }
#pragma unroll
    for (int nt = 0; nt < 4; ++nt) {
      int token = nt * 16 + l16;
      float mu = muS[token], rs = rstdS[token];
      float fs = 0.f;
#pragma unroll
      for (int mt = 0; mt < 4; ++mt) {
        float y0 = (acc2[mt][nt][0] - mu) * rs * g[mt].x + be[mt].x;
        float y1 = (acc2[mt][nt][1] - mu) * rs * g[mt].y + be[mt].y;
        float y2 = (acc2[mt][nt][2] - mu) * rs * g[mt].z + be[mt].z;
        float y3 = (acc2[mt][nt][3] - mu) * rs * g[mt].w + be[mt].w;
        fs += y0 * y0 + y1 * y1 + y2 * y2 + y3 * y3;
        unsigned int p0 = f2b(y0) | ((unsigned int)f2b(y1) << 16);
        unsigned int p1 = f2b(y2) | ((unsigned int)f2b(y3) << 16);
        *(uint2*)(&Xs[token * XP + wid * 64 + mt * 16 + quad * 4]) =
            make_uint2(p0, p1);
      }
      fs += __shfl_xor(fs, 16, 64);
      fs += __shfl_xor(fs, 32, 64);
      if (quad == 0) fsqp[wid * 64 + token] = fs;
    }
  }
  __syncthreads();
  if (tid < 64)
    fsqS[tid] = fsqp[tid] + fsqp[64 + tid] + fsqp[128 + tid] + fsqp[192 + tid];
  __syncthreads();

  // ---- Phase 3: dots GEMM: this wave's 16 tokens vs 64 (padded) memory rows ----
  f32x4 acc3[4];
#pragma unroll
  for (int nt = 0; nt < 4; ++nt) {
    acc3[nt][0] = 0.f; acc3[nt][1] = 0.f; acc3[nt][2] = 0.f; acc3[nt][3] = 0.f;
  }
#pragma unroll
  for (int kk = 0; kk < 8; ++kk) {
    int k0 = kk * 32 + quad * 8;
    bf16x8 a = *(const bf16x8*)(Xs + (wid * 16 + l16) * XP + k0);
#pragma unroll
    for (int nt = 0; nt < 4; ++nt) {
      bf16x8 b = *(const bf16x8*)(memB + (nt * 16 + l16) * 256 + k0);
      acc3[nt] = __builtin_amdgcn_mfma_f32_16x16x32_bf16(a, b, acc3[nt], 0, 0, 0);
    }
  }
  {
    float4 fsq4 = *(const float4*)(&fsqS[wid * 16 + quad * 4]);
#pragma unroll
    for (int nt = 0; nt < 4; ++nt) {
      int col = nt * 16 + l16;
      float mq = msq[col];
#pragma unroll
      for (int r = 0; r < 4; ++r) {
        float fv = (r == 0) ? fsq4.x : (r == 1) ? fsq4.y : (r == 2) ? fsq4.z : fsq4.w;
        float d2 = fv + mq - 2.f * acc3[nt][r];
        float d = sqrtf(fmaxf(d2, 0.f));
        int row = wid * 16 + quad * 4 + r;
        distS[row * DPitch + col] = d;
      }
    }
  }
  __syncthreads();

  // ---- Phase 4: top-5 smallest of 50, mean, sigmoid ----
  if (tid < 64) {
    float b0 = 1e30f, b1 = 1e30f, b2 = 1e30f, b3 = 1e30f, b4 = 1e30f;
    const float* dr = &distS[tid * DPitch];
    for (int j = 0; j < 50; ++j) {
      float v = dr[j];
      b4 = fminf(b4, v);
      float t;
      if (b4 < b3) { t = b3; b3 = b4; b4 = t; }
      if (b3 < b2) { t = b2; b2 = b3; b3 = t; }
      if (b2 < b1) { t = b1; b1 = b2; b2 = t; }
      if (b1 < b0) { t = b0; b0 = b1; b1 = t; }
    }
    float avg = (b0 + b1 + b2 + b3 + b4) * 0.2f;
    float sarg = avg - 1.f;
    out[blockIdx.x * 64 + tid] = 1.f / (1.f + __expf(-sarg));
  }
}

// ---------------- launch ----------------
extern "C" void kernel_launch(void* const* d_in, const int* in_sizes, int n_in,
                              void* d_out, int out_size, void* d_ws, size_t ws_size,
                              hipStream_t stream) {
  const float* X   = (const float*)d_in[0];  // [8*8192][256]
  const float* mem = (const float*)d_in[1];  // [50][256]
  const float* W1  = (const float*)d_in[2];  // [256][512]
  const float* b1  = (const float*)d_in[3];  // [512]
  const float* W2  = (const float*)d_in[4];  // [512][256]
  const float* b2  = (const float*)d_in[5];  // [256]
  const float* g   = (const float*)d_in[6];  // [256]
  const float* be  = (const float*)d_in[7];  // [256]
  float* out = (float*)d_out;                // [65536]

  unsigned short* W1T  = (unsigned short*)d_ws;   // [512][256] bf16
  unsigned short* W2T  = W1T + 131072;            // [256][512] bf16
  unsigned short* memB = W2T + 131072;            // [64][256] bf16
  float* msq = (float*)(memB + 16384);            // [64] fp32

  prep_weights<<<1088, 256, 0, stream>>>(W1, W2, mem, W1T, W2T, memB);
  prep_msq<<<64, 64, 0, stream>>>(mem, msq);
  fused_main<<<1024, 256, 0, stream>>>(X, b1, b2, g, be, W1T, W2T, memB, msq, out);
}